// Round 7
// baseline (679.450 us; speedup 1.0000x reference)
//
#include <hip/hip_runtime.h>
#include <cmath>

#define BATCH 4
#define CH    512
#define HCH   256
#define NPIX  4096
#define L2E   1.44269504088896340736f

typedef __attribute__((ext_vector_type(8))) short bf16x8;
typedef __attribute__((ext_vector_type(4))) float f32x4;

#define MFMA16(a, b, c) __builtin_amdgcn_mfma_f32_16x16x32_bf16((a), (b), (c), 0, 0, 0)

__device__ __forceinline__ unsigned short f2bf(float f) {
    unsigned int u = __float_as_uint(f);
    return (unsigned short)((u + 0x7fffu + ((u >> 16) & 1u)) >> 16);
}
__device__ __forceinline__ ushort4 pack4(float a, float b, float c, float d) {
    ushort4 u; u.x = f2bf(a); u.y = f2bf(b); u.z = f2bf(c); u.w = f2bf(d); return u;
}

// ---------------------------------------------------------------------------
// Wc[1024][512] bf16 = concat(Wf, Wg, Wh) rows, K-contiguous.
// ---------------------------------------------------------------------------
__global__ __launch_bounds__(256) void convert_w_kernel(
    const float* __restrict__ Wf, const float* __restrict__ Wg,
    const float* __restrict__ Wh, unsigned short* __restrict__ Wc)
{
    const int idx = blockIdx.x * 256 + threadIdx.x;
    const int o  = idx >> 7;
    const int c4 = (idx & 127) * 4;
    const float* src = (o < HCH)     ? (Wf + (size_t)o * CH + c4)
                     : (o < 2 * HCH) ? (Wg + (size_t)(o - HCH) * CH + c4)
                                     : (Wh + (size_t)(o - 2 * HCH) * CH + c4);
    float4 v = *(const float4*)src;
    *(ushort4*)&Wc[(size_t)o * CH + c4] = pack4(v.x, v.y, v.z, v.w);
}

// ---------------------------------------------------------------------------
// X' swizzle: x fp32 [b][512][4096] -> bf16 [b][cb=16][n=4096][co=32].
// ---------------------------------------------------------------------------
__global__ __launch_bounds__(256) void convert_x_kernel(
    const float* __restrict__ x, unsigned short* __restrict__ Xp)
{
    __shared__ unsigned short Lt[64][40];
    const int b  = blockIdx.z;
    const int cb = blockIdx.y;
    const int n0 = blockIdx.x * 64;
    const int t  = threadIdx.x;
    const int cr = t >> 4;
    const int f4 = t & 15;
    #pragma unroll
    for (int p = 0; p < 2; ++p) {
        const int c = p * 16 + cr;
        float4 v = *(const float4*)(x + ((size_t)b * CH + cb * 32 + c) * NPIX + n0 + f4 * 4);
        Lt[f4 * 4 + 0][c] = f2bf(v.x);
        Lt[f4 * 4 + 1][c] = f2bf(v.y);
        Lt[f4 * 4 + 2][c] = f2bf(v.z);
        Lt[f4 * 4 + 3][c] = f2bf(v.w);
    }
    __syncthreads();
    const int n  = t >> 2;
    const int ch = t & 3;
    uint4 u = *(const uint4*)&Lt[n][ch * 8];
    *(uint4*)&Xp[((size_t)b * 16 + cb) * (NPIX * 32) + (size_t)(n0 + n) * 32 + ch * 8] = u;
}

// ---------------------------------------------------------------------------
// proj F/G (unchanged)
// ---------------------------------------------------------------------------
__global__ __launch_bounds__(256, 2) void proj_fg_kernel(
    const unsigned short* __restrict__ Wc, const unsigned short* __restrict__ Xp,
    const float* __restrict__ bf, const float* __restrict__ bg,
    unsigned short* __restrict__ F, unsigned short* __restrict__ G)
{
    const int b  = blockIdx.z;
    const int n0 = blockIdx.x * 128;
    const int o0 = blockIdx.y * 128;
    const int t  = threadIdx.x;
    const int wave = t >> 6, lane = t & 63, quad = lane >> 4, l16 = lane & 15;
    const int ow = o0 + wave * 32;

    f32x4 acc[2][8];
    #pragma unroll
    for (int ms = 0; ms < 2; ++ms)
        #pragma unroll
        for (int ns = 0; ns < 8; ++ns) acc[ms][ns] = (f32x4){0.f, 0.f, 0.f, 0.f};

    const unsigned short* xb = Xp + (size_t)b * 16 * (NPIX * 32);
    for (int st = 0; st < 16; ++st) {
        bf16x8 a0 = *(const bf16x8*)&Wc[(size_t)(ow + l16) * CH + st * 32 + quad * 8];
        bf16x8 a1 = *(const bf16x8*)&Wc[(size_t)(ow + 16 + l16) * CH + st * 32 + quad * 8];
        const unsigned short* xs = xb + (size_t)st * (NPIX * 32) + quad * 8;
        #pragma unroll
        for (int ns = 0; ns < 8; ++ns) {
            bf16x8 bb = *(const bf16x8*)(xs + (size_t)(n0 + ns * 16 + l16) * 32);
            acc[0][ns] = MFMA16(a0, bb, acc[0][ns]);
            acc[1][ns] = MFMA16(a1, bb, acc[1][ns]);
        }
    }

    const int orow = quad * 4;
    #pragma unroll
    for (int ms = 0; ms < 2; ++ms) {
        const int ob = ow + ms * 16 + orow;
        float bias[4];
        #pragma unroll
        for (int r = 0; r < 4; ++r)
            bias[r] = (o0 < HCH) ? bf[ob + r] : bg[ob + r - HCH];
        #pragma unroll
        for (int ns = 0; ns < 8; ++ns) {
            const int n = n0 + ns * 16 + l16;
            ushort4 u = pack4(acc[ms][ns][0] + bias[0], acc[ms][ns][1] + bias[1],
                              acc[ms][ns][2] + bias[2], acc[ms][ns][3] + bias[3]);
            if (o0 < HCH) {
                *(ushort4*)&F[((size_t)b * NPIX + n) * HCH + ob] = u;
            } else {
                const int og = ob - HCH;
                const int cb = og >> 5, co = og & 31;
                *(ushort4*)&G[((size_t)b * 8 + cb) * (NPIX * 32) + (size_t)n * 32 + co] = u;
            }
        }
    }
}

// ---------------------------------------------------------------------------
// proj V (unchanged)
// ---------------------------------------------------------------------------
__global__ __launch_bounds__(256, 2) void proj_v_kernel(
    const unsigned short* __restrict__ Wc, const unsigned short* __restrict__ Xp,
    const float* __restrict__ bh, unsigned short* __restrict__ V)
{
    const int b  = blockIdx.z;
    const int c0 = blockIdx.x * 128;
    const int p0 = blockIdx.y * 128;
    const int t  = threadIdx.x;
    const int wave = t >> 6, lane = t & 63, quad = lane >> 4, l16 = lane & 15;
    const int pw = p0 + wave * 32;

    f32x4 acc[2][8];
    #pragma unroll
    for (int ms = 0; ms < 2; ++ms)
        #pragma unroll
        for (int ns = 0; ns < 8; ++ns) acc[ms][ns] = (f32x4){0.f, 0.f, 0.f, 0.f};

    const unsigned short* xb = Xp + (size_t)b * 16 * (NPIX * 32);
    for (int st = 0; st < 16; ++st) {
        const unsigned short* xs = xb + (size_t)st * (NPIX * 32) + quad * 8;
        bf16x8 a0 = *(const bf16x8*)(xs + (size_t)(pw + l16) * 32);
        bf16x8 a1 = *(const bf16x8*)(xs + (size_t)(pw + 16 + l16) * 32);
        #pragma unroll
        for (int ns = 0; ns < 8; ++ns) {
            bf16x8 bb = *(const bf16x8*)&Wc[(size_t)(2 * HCH + c0 + ns * 16 + l16) * CH + st * 32 + quad * 8];
            acc[0][ns] = MFMA16(a0, bb, acc[0][ns]);
            acc[1][ns] = MFMA16(a1, bb, acc[1][ns]);
        }
    }

    float biasv[8];
    #pragma unroll
    for (int ns = 0; ns < 8; ++ns) biasv[ns] = bh[c0 + ns * 16 + l16];

    const int kb = pw >> 5;
    const int ko0 = quad * 4;
    #pragma unroll
    for (int ms = 0; ms < 2; ++ms) {
        #pragma unroll
        for (int ns = 0; ns < 8; ++ns) {
            const int c = c0 + ns * 16 + l16;
            ushort4 u = pack4(acc[ms][ns][0] + biasv[ns], acc[ms][ns][1] + biasv[ns],
                              acc[ms][ns][2] + biasv[ns], acc[ms][ns][3] + biasv[ns]);
            *(ushort4*)&V[((size_t)b * 128 + kb) * (CH * 32) + (size_t)c * 32 + ms * 16 + ko0] = u;
        }
    }
}

// ---------------------------------------------------------------------------
// Fused attention: phase 1 = softmax denominators (barrier-free QK sweep),
// phase 2 = P + colsums + PV with BK=256 and drain-friendly barrier placement.
// Block: 64q x 256c-half, 512 thr. grid 512, XCD map b=xcd>>1, ch=xcd&1.
// ---------------------------------------------------------------------------
#define QK_TILE(K0) do {                                                        \
    const int kk_ = (K0) + kw * 64;                                             \
    _Pragma("unroll")                                                           \
    for (int qs_ = 0; qs_ < 2; ++qs_)                                           \
        _Pragma("unroll")                                                       \
        for (int ks_ = 0; ks_ < 4; ++ks_) s[qs_][ks_] = (f32x4){0.f,0.f,0.f,0.f}; \
    _Pragma("unroll")                                                           \
    for (int st_ = 0; st_ < 8; ++st_) {                                         \
        bf16x8 a0_ = *(const bf16x8*)(Fb + (size_t)l16 * HCH + st_ * 32 + quad * 8);        \
        bf16x8 a1_ = *(const bf16x8*)(Fb + (size_t)(16 + l16) * HCH + st_ * 32 + quad * 8); \
        const unsigned short* gs_ = Gb + (size_t)st_ * (NPIX * 32) + quad * 8;  \
        _Pragma("unroll")                                                       \
        for (int ks_ = 0; ks_ < 4; ++ks_) {                                     \
            bf16x8 g_ = *(const bf16x8*)(gs_ + (size_t)(kk_ + ks_ * 16 + l16) * 32); \
            s[0][ks_] = MFMA16(a0_, g_, s[0][ks_]);                             \
            s[1][ks_] = MFMA16(a1_, g_, s[1][ks_]);                             \
        }                                                                       \
    } } while (0)

__global__ __launch_bounds__(512, 4) void fused_attn_kernel(
    const unsigned short* __restrict__ F, const unsigned short* __restrict__ G,
    const unsigned short* __restrict__ V,
    float* __restrict__ outres, float* __restrict__ attnacc)
{
    __shared__ unsigned short P[64][264];   // 33.8 KB, pitch 264
    __shared__ float red[4][64];
    const int blk = blockIdx.x;
    const int xcd = blk & 7;
    const int b   = xcd >> 1;
    const int ch  = xcd & 1;
    const int q0  = (blk >> 3) * 64;
    const int t    = threadIdx.x;
    const int wave = t >> 6, lane = t & 63, quad = lane >> 4, l16 = lane & 15;
    const int qh = wave >> 2, kw = wave & 3;
    const int cw = ch * 256 + wave * 32;

    const unsigned short* Fb = F + ((size_t)b * NPIX + q0 + qh * 32) * HCH;
    const unsigned short* Gb = G + (size_t)b * 8 * (NPIX * 32);
    const unsigned short* Vb = V + (size_t)b * 128 * (CH * 32);

    f32x4 s[2][4];

    // ---- phase 1: softmax denominators (m = 0), no barriers ----
    float ls[2][4];
    #pragma unroll
    for (int qs = 0; qs < 2; ++qs)
        #pragma unroll
        for (int r = 0; r < 4; ++r) ls[qs][r] = 0.f;

    for (int k0 = 0; k0 < NPIX; k0 += 256) {
        QK_TILE(k0);
        #pragma unroll
        for (int qs = 0; qs < 2; ++qs)
            #pragma unroll
            for (int r = 0; r < 4; ++r)
                ls[qs][r] += exp2f(L2E * s[qs][0][r]) + exp2f(L2E * s[qs][1][r])
                           + exp2f(L2E * s[qs][2][r]) + exp2f(L2E * s[qs][3][r]);
    }
    #pragma unroll
    for (int d = 1; d < 16; d <<= 1)
        #pragma unroll
        for (int qs = 0; qs < 2; ++qs)
            #pragma unroll
            for (int r = 0; r < 4; ++r) ls[qs][r] += __shfl_xor(ls[qs][r], d, 64);
    if (l16 == 0) {
        #pragma unroll
        for (int qs = 0; qs < 2; ++qs)
            #pragma unroll
            for (int r = 0; r < 4; ++r)
                red[kw][qh * 32 + qs * 16 + quad * 4 + r] = ls[qs][r];
    }
    __syncthreads();
    float linv[2][4];
    #pragma unroll
    for (int qs = 0; qs < 2; ++qs)
        #pragma unroll
        for (int r = 0; r < 4; ++r) {
            const int qi = qh * 32 + qs * 16 + quad * 4 + r;
            linv[qs][r] = 1.0f / (red[0][qi] + red[1][qi] + red[2][qi] + red[3][qi]);
        }

    // ---- phase 2: P, colsums, PV ----
    f32x4 O[4][2];
    #pragma unroll
    for (int qs = 0; qs < 4; ++qs)
        #pragma unroll
        for (int ct = 0; ct < 2; ++ct) O[qs][ct] = (f32x4){0.f, 0.f, 0.f, 0.f};

    QK_TILE(0);
    for (int k0 = 0; k0 < NPIX; k0 += 256) {
        const int kk = k0 + kw * 64;
        // exp + P write + colsum accumulation (consumes s)
        float cs[4] = {0.f, 0.f, 0.f, 0.f};
        #pragma unroll
        for (int qs = 0; qs < 2; ++qs)
            #pragma unroll
            for (int ks = 0; ks < 4; ++ks)
                #pragma unroll
                for (int r = 0; r < 4; ++r) {
                    const float pv = exp2f(L2E * s[qs][ks][r]) * linv[qs][r];
                    P[qh * 32 + qs * 16 + quad * 4 + r][kw * 64 + ks * 16 + l16] = f2bf(pv);
                    cs[ks] += pv;
                }
        if (ch == 0) {
            #pragma unroll
            for (int ks = 0; ks < 4; ++ks) {
                float c = cs[ks];
                c += __shfl_xor(c, 16, 64);
                c += __shfl_xor(c, 32, 64);
                if (quad == 0)
                    atomicAdd(&attnacc[(size_t)b * NPIX + kk + ks * 16 + l16], c);
            }
        }
        __syncthreads();   // A: P complete (prior PV protected by barrier B)

        // PV over the 256-key tile, wave's 32-c strip
        #pragma unroll
        for (int ks2 = 0; ks2 < 8; ++ks2) {
            bf16x8 pa[4];
            #pragma unroll
            for (int qs = 0; qs < 4; ++qs)
                pa[qs] = *(const bf16x8*)&P[qs * 16 + l16][ks2 * 32 + quad * 8];
            const unsigned short* vs = Vb + ((size_t)(k0 >> 5) + ks2) * (CH * 32) + quad * 8;
            bf16x8 vb0 = *(const bf16x8*)(vs + (size_t)(cw + l16) * 32);
            bf16x8 vb1 = *(const bf16x8*)(vs + (size_t)(cw + 16 + l16) * 32);
            #pragma unroll
            for (int qs = 0; qs < 4; ++qs) {
                O[qs][0] = MFMA16(pa[qs], vb0, O[qs][0]);
                O[qs][1] = MFMA16(pa[qs], vb1, O[qs][1]);
            }
        }

        // next tile's QK while P is still being read elsewhere (no P access)
        if (k0 + 256 < NPIX) QK_TILE(k0 + 256);
        __syncthreads();   // B: PV reads done -> next P write is safe
    }

    #pragma unroll
    for (int qs = 0; qs < 4; ++qs) {
        #pragma unroll
        for (int ct = 0; ct < 2; ++ct) {
            const int c = cw + ct * 16 + l16;
            *(f32x4*)&outres[((size_t)b * CH + c) * NPIX + q0 + qs * 16 + quad * 4] = O[qs][ct];
        }
    }
}

__global__ __launch_bounds__(256) void attn_fin_kernel(
    const float* __restrict__ acc, float* __restrict__ outa)
{
    const int i = blockIdx.x * 256 + threadIdx.x;
    if (i < BATCH * NPIX) outa[i] = acc[i] * (1.0f / (float)NPIX);
}

extern "C" void kernel_launch(void* const* d_in, const int* in_sizes, int n_in,
                              void* d_out, int out_size, void* d_ws, size_t ws_size,
                              hipStream_t stream)
{
    (void)in_sizes; (void)n_in; (void)out_size; (void)ws_size;
    const float* x  = (const float*)d_in[0];
    const float* Wf = (const float*)d_in[1];
    const float* bf = (const float*)d_in[2];
    const float* Wg = (const float*)d_in[3];
    const float* bg = (const float*)d_in[4];
    const float* Wh = (const float*)d_in[5];
    const float* bh = (const float*)d_in[6];
    float* out = (float*)d_out;

    unsigned short* Xp = (unsigned short*)d_ws;                      // 4*16*4096*32
    unsigned short* Wc = Xp + (size_t)BATCH * 16 * NPIX * 32;        // 1024*512
    unsigned short* F  = Wc + (size_t)1024 * CH;                     // 4*4096*256
    unsigned short* G  = F + (size_t)BATCH * NPIX * HCH;             // 4*8*4096*32
    unsigned short* V  = G + (size_t)BATCH * NPIX * HCH;             // 4*128*512*32
    float* attnacc = (float*)(V + (size_t)BATCH * NPIX * CH);        // 4*4096

    hipMemsetAsync(attnacc, 0, (size_t)BATCH * NPIX * sizeof(float), stream);

    convert_w_kernel<<<512, 256, 0, stream>>>(Wf, Wg, Wh, Wc);
    convert_x_kernel<<<dim3(NPIX / 64, 16, BATCH), 256, 0, stream>>>(x, Xp);

    proj_fg_kernel<<<dim3(NPIX / 128, 4, BATCH), 256, 0, stream>>>(Wc, Xp, bf, bg, F, G);
    proj_v_kernel<<<dim3(4, NPIX / 128, BATCH), 256, 0, stream>>>(Wc, Xp, bh, V);

    fused_attn_kernel<<<512, 512, 0, stream>>>(F, G, V, out, attnacc);

    attn_fin_kernel<<<BATCH * NPIX / 256, 256, 0, stream>>>(
        attnacc, out + (size_t)BATCH * CH * NPIX);
}